// Round 2
// baseline (457.513 us; speedup 1.0000x reference)
//
#include <hip/hip_runtime.h>

// BuildingModule: B=8192 sequential chains, T=1024 steps, u:(B,T,8) f32, out:(B,T,3) f32.
//
// R5: fix R4's regression. Evidence: VGPR_Count=80 < the 96+ VGPRs the declared
// double-buffered broadcast sets need -> the scheduler sank/split the LDS reads
// into the compute loop, exposing ~120cy ds_read latency per use (163us kernel,
// VALUBusy 27%, ~380 cy/step vs ~100 cy/step issue floor).
//
// Changes:
//  (1) 16B broadcast rows: (u0, G0', G1', G2') instead of 24B. E_k = hce_k*u0
//      recomputed in-lane (3 muls, parallel with the rcp -> off critical path).
//      DS ops/body: 18 -> 9; double-buffer register sets: 96 -> 64 VGPRs.
//  (2) __builtin_amdgcn_sched_barrier(0) after each body's issue phase so the
//      ds_reads/global loads CANNOT sink into compute; each set's lgkm wait is
//      covered by a full 8-step compute phase.
//  (3) Uniform lam-derived coefficients forced to SGPRs via readfirstlane.
//
// Same verified-correct algebra as R4 (i_k*X_k = 1 + O(ulp) chain compression),
// same wave-synchronous LDS broadcast (8 lanes/chain within one wave, in-order
// DS pipe, no barriers), same XOR-swizzled slot layout (reads conflict-free:
// bank-quad g + 2*((i^g)&3) mod 8 is a permutation of 0..7 for every row i).

#if __has_builtin(__builtin_amdgcn_exp2f)
#define EXP2F(x) __builtin_amdgcn_exp2f(x)
#else
#define EXP2F(x) __expf((x) * 0.69314718056f)
#endif

namespace {
constexpr int T = 1024;
constexpr int NBLK = T / 8;           // 128 blocks of 8 rows
constexpr float LOG2E = 1.4426950408889634f;
constexpr int CH_STRIDE = 68;         // floats per chain LDS region (8 slots * 8 + 4 pad)
}

__device__ __forceinline__ float rfl(float x) {
    return __int_as_float(__builtin_amdgcn_readfirstlane(__float_as_int(x)));
}

__global__ __launch_bounds__(256, 1) void bm_fwd(
    const float* __restrict__ x0p,   // (B,3)
    const float* __restrict__ up,    // (B,T,8)
    const float* __restrict__ lamp,  // (14)
    float* __restrict__ outp)        // (B,T,3)
{
    // 32 chains/WG * 272B, XOR-swizzled row slots: row r of chain g -> slot (r^g).
    __shared__ float lds[32 * CH_STRIDE];

    const int tid   = blockIdx.x * 256 + threadIdx.x;
    const int chain = tid >> 3;
    const int phase = tid & 7;
    const int g     = (threadIdx.x >> 3) & 7;   // group within wave
    float* __restrict__ region = lds + (threadIdx.x >> 3) * CH_STRIDE;
    float* __restrict__ wslot  = region + ((phase ^ g) << 3);

    // lam -> exponentials (uniform; precise expf once per thread, then SGPR'd)
    float e[14];
#pragma unroll
    for (int i = 0; i < 14; ++i) e[i] = expf(lamp[i]);

    // H/C in log2 domain, folded into every coefficient; all wave-uniform -> SGPR
    const float hc0 = (60.0f / 10665991.0f) * LOG2E;
    const float hc1 = (60.0f / 27000000.0f) * LOG2E;
    const float hc2 = (60.0f / 7953253.0f) * LOG2E;
    const float F12_0 = rfl(hc0 * e[0]), F12_1 = rfl(hc1 * e[0]);
    const float F23_1 = rfl(hc1 * e[1]), F23_2 = rfl(hc2 * e[1]);
    const float hce0 = rfl(hc0 * e[2]),  hce1 = rfl(hc1 * e[3]),  hce2 = rfl(hc2 * e[4]);
    const float ss0  = rfl(hc0 * e[5]),  ss1  = rfl(hc1 * e[6]),  ss2  = rfl(hc2 * e[7]);
    const float sh0  = rfl(hc0 * e[8]),  sh1  = rfl(hc1 * e[9]),  sh2  = rfl(hc2 * e[10]);
    const float sc0  = rfl(hc0 * e[11]), sc1  = rfl(hc1 * e[12]), sc2  = rfl(hc2 * e[13]);
    // -F constants folded into the G' bias
    const float g0c = rfl(-hce0 - F12_0);
    const float g1c = rfl(-hce1 - F12_1 - F23_1);
    const float g2c = rfl(-hce2 - F23_2);

    float X0 = x0p[3 * chain + 0];
    float X1 = x0p[3 * chain + 1];
    float X2 = x0p[3 * chain + 2];

    const float4* __restrict__ ub = (const float4*)(up + (size_t)chain * (T * 8));
    float* __restrict__ ob = outp + (size_t)chain * (T * 3);

    // pre-fold my row into (u0, G0', G1', G2'), write 16B to my LDS slot; return my u0
    auto fold_write = [&](const float4& r0, const float4& r1) -> float {
        const float G0 = fmaf(sc0, r1.y, fmaf(sh0, r0.z, fmaf(ss0, r0.y, g0c)));
        const float G1 = fmaf(sc1, r1.z, fmaf(sh1, r0.w, fmaf(ss1, r0.y, g1c)));
        const float G2 = fmaf(sc2, r1.w, fmaf(sh2, r1.x, fmaf(ss2, r0.y, g2c)));
        *(float4*)wslot = make_float4(r0.x, G0, G1, G2);
        return r0.x;
    };

    // hoisted conflict-free broadcast reads of all 8 rows into a register set
    auto issue_reads = [&](float4 (&A)[8]) {
#pragma unroll
        for (int i = 0; i < 8; ++i) {
            A[i] = *(float4*)(region + ((i ^ g) << 3));
        }
    };

    // 8 steps of block j from a register set; store my output row
    auto compute = [&](int j, const float4 (&A)[8], float myu0) {
        float O0 = 0.0f, O1 = 0.0f, O2 = 0.0f;
#pragma unroll
        for (int i = 0; i < 8; ++i) {
            if (phase == i) { O0 = X0; O1 = X1; O2 = X2; }   // state BEFORE row 8j+i
            const float u0b = A[i].x;
            const float E0 = hce0 * u0b;
            const float E1 = hce1 * u0b;
            const float E2 = hce2 * u0b;
            const float i0 = __builtin_amdgcn_rcpf(X0);
            const float i1 = __builtin_amdgcn_rcpf(X1);
            const float i2 = __builtin_amdgcn_rcpf(X2);
            // p_k parallel with the rcp (depend only on X and u0)
            const float p0 = fmaf(F12_0, X1, E0);
            const float p1 = fmaf(F12_1, X0, fmaf(F23_1, X2, E1));
            const float p2 = fmaf(F23_2, X1, E2);
            const float z0 = fmaf(i0, p0, A[i].y);   // A.y = G0'
            const float z1 = fmaf(i1, p1, A[i].z);   // A.z = G1'
            const float z2 = fmaf(i2, p2, A[i].w);   // A.w = G2'
            X0 *= EXP2F(z0);
            X1 *= EXP2F(z1);
            X2 *= EXP2F(z2);
        }
        const bool bad = (myu0 < 1e-6f) && !((j == 0) & (phase == 0));
        float3 o;
        o.x = bad ? -1.0f : O0;
        o.y = bad ? -1.0f : O1;
        o.z = bad ? -1.0f : O2;
        *(float3*)(ob + (size_t)((j << 3) + phase) * 3) = o;
    };

    float4 setA[8], setB[8];
    float4 rE0, rE1, rO0, rO1;   // raw u rows in flight (even/odd bodies)
    float myu0A, myu0B;

    // prologue: block 0 folded+read into set A; blocks 1,2 in flight in regs
    {
        const float4* s0 = ub + (size_t)((0 + phase) * 2);   // block 0 (wait target)
        float4 t0 = s0[0], t1 = s0[1];
        const float4* s1 = ub + (size_t)((8 + phase) * 2);   // block 1
        rE0 = s1[0]; rE1 = s1[1];
        const float4* s2 = ub + (size_t)((16 + phase) * 2);  // block 2
        rO0 = s2[0]; rO1 = s2[1];
        myu0A = fold_write(t0, t1);
        issue_reads(setA);
        __builtin_amdgcn_sched_barrier(0);
    }

    // invariant entering the even body at j: rE = block j+1, rO = block j+2,
    // set A holds block j (reads issued, not yet waited), myu0A = my u0 for block j.
    for (int j = 0; j < NBLK; j += 2) {
        // even body: prepare set B (block j+1), compute block j from set A
        myu0B = fold_write(rE0, rE1);                         // block j+1 -> LDS
        {
            const int jj = (j + 3 < NBLK) ? (j + 3) : (NBLK - 1);
            const float4* s = ub + (size_t)(((jj << 3) + phase) * 2);
            rE0 = s[0]; rE1 = s[1];                           // block j+3
        }
        issue_reads(setB);                                    // reads for j+1
        __builtin_amdgcn_sched_barrier(0);                    // pin: no sinking into compute
        compute(j, setA, myu0A);                              // lgkm covered by this body's issue

        // odd body: prepare set A (block j+2), compute block j+1 from set B
        myu0A = fold_write(rO0, rO1);                         // block j+2 (tail: clamped dup, unused)
        {
            const int jj = (j + 4 < NBLK) ? (j + 4) : (NBLK - 1);
            const float4* s = ub + (size_t)(((jj << 3) + phase) * 2);
            rO0 = s[0]; rO1 = s[1];                           // block j+4
        }
        issue_reads(setA);                                    // reads for j+2
        __builtin_amdgcn_sched_barrier(0);
        compute(j + 1, setB, myu0B);
    }
}

extern "C" void kernel_launch(void* const* d_in, const int* in_sizes, int n_in,
                              void* d_out, int out_size, void* d_ws, size_t ws_size,
                              hipStream_t stream) {
    const float* x0  = (const float*)d_in[0];   // (B,3)
    const float* u   = (const float*)d_in[1];   // (B,T,8)
    const float* lam = (const float*)d_in[2];   // (14)
    float* out = (float*)d_out;                 // (B,T,3)

    const int B = in_sizes[0] / 3;              // 8192
    const int threads = B * 8;                  // 8 lanes per chain
    dim3 grid(threads / 256), block(256);
    hipLaunchKernelGGL(bm_fwd, grid, block, 0, stream, x0, u, lam, out);
}

// Round 3
// 436.005 us; speedup vs baseline: 1.0493x; 1.0493x over previous
//
#include <hip/hip_runtime.h>

// BuildingModule: B=8192 sequential chains, T=1024 steps, u:(B,T,8) f32, out:(B,T,3) f32.
//
// R6: occupancy fix. R3-R5 all measured ~430 cy/step vs ~60 cy/step issue floor
// at 1 wave/SIMD (VALUBusy 27%, HBM 16%, Occupancy 10.4%); two rounds of
// source-level pipelining failed to remove the exposed stalls (VGPR_Count
// pinned at 80 -> compiler collapses prefetch distance). At 1 wave/SIMD every
// exposed waitcnt is wall time. Fix: 16 lanes/chain -> 2048 waves = 2
// waves/SIMD. Redundant issue doubles (still ~62 cy/step/wave) but hardware
// TLP now hides DS/vmcnt/trans latency regardless of compiler waitcnt
// placement. Issue floor ~53 us vs measured 183 us.
//
// Structure: superblock = 16 rows. Lane l of a chain owns row sb*16+l:
//  - folds it to (u0, G0', G1', G2') (same verified algebra as R4/R5:
//    i_k*X_k = 1+O(ulp) chain compression, -F folded into G'),
//  - writes 16B to its slot in the chain's LDS buffer (double-buffered),
//  - per step i: ALL 16 lanes ds_read_b128 the SAME slot i (hardware
//    broadcast, conflict-free; 4 chain-groups/wave on disjoint bank quads
//    via 132-float region stride), compute the X update redundantly,
//  - lane l captures X before step l -> output row sb*16+l, masked by its
//    own u0.
// Wave-synchronous (16 lanes within one wave, in-order DS pipe) -> no
// barriers. Global prefetch 1 superblock ahead (~1000 cy in flight).

#if __has_builtin(__builtin_amdgcn_exp2f)
#define EXP2F(x) __builtin_amdgcn_exp2f(x)
#else
#define EXP2F(x) __expf((x) * 0.69314718056f)
#endif

namespace {
constexpr int T = 1024;
constexpr int SB = 16;                 // rows per superblock = lanes per chain
constexpr int NSB = T / SB;            // 64 superblocks
constexpr float LOG2E = 1.4426950408889634f;
constexpr int CH_STRIDE = 132;         // floats per chain region: 2 bufs * 16 slots * 4 + 4 pad
}

__device__ __forceinline__ float rfl(float x) {
    return __int_as_float(__builtin_amdgcn_readfirstlane(__float_as_int(x)));
}

__global__ __launch_bounds__(256, 2) void bm_fwd(
    const float* __restrict__ x0p,   // (B,3)
    const float* __restrict__ up,    // (B,T,8)
    const float* __restrict__ lamp,  // (14)
    float* __restrict__ outp)        // (B,T,3)
{
    // 16 chains/WG * 528B = 8448B
    __shared__ float lds[16 * CH_STRIDE];

    const int tid   = blockIdx.x * 256 + threadIdx.x;
    const int chain = tid >> 4;            // global chain id
    const int l     = tid & 15;            // lane-in-chain = row phase
    float* __restrict__ region = lds + (threadIdx.x >> 4) * CH_STRIDE;

    // lam -> exponentials (uniform; precise expf once per thread, then SGPR'd)
    float e[14];
#pragma unroll
    for (int i = 0; i < 14; ++i) e[i] = expf(lamp[i]);

    // H/C in log2 domain, folded into every coefficient; wave-uniform -> SGPR
    const float hc0 = (60.0f / 10665991.0f) * LOG2E;
    const float hc1 = (60.0f / 27000000.0f) * LOG2E;
    const float hc2 = (60.0f / 7953253.0f) * LOG2E;
    const float F12_0 = rfl(hc0 * e[0]), F12_1 = rfl(hc1 * e[0]);
    const float F23_1 = rfl(hc1 * e[1]), F23_2 = rfl(hc2 * e[1]);
    const float hce0 = rfl(hc0 * e[2]),  hce1 = rfl(hc1 * e[3]),  hce2 = rfl(hc2 * e[4]);
    const float ss0  = rfl(hc0 * e[5]),  ss1  = rfl(hc1 * e[6]),  ss2  = rfl(hc2 * e[7]);
    const float sh0  = rfl(hc0 * e[8]),  sh1  = rfl(hc1 * e[9]),  sh2  = rfl(hc2 * e[10]);
    const float sc0  = rfl(hc0 * e[11]), sc1  = rfl(hc1 * e[12]), sc2  = rfl(hc2 * e[13]);
    const float g0c = rfl(-hce0 - F12_0);
    const float g1c = rfl(-hce1 - F12_1 - F23_1);
    const float g2c = rfl(-hce2 - F23_2);

    float X0 = x0p[3 * chain + 0];
    float X1 = x0p[3 * chain + 1];
    float X2 = x0p[3 * chain + 2];

    const float4* __restrict__ ub = (const float4*)(up + (size_t)chain * (T * 8));
    float* __restrict__ ob = outp + (size_t)chain * (T * 3);

    // fold my row -> (u0, G0', G1', G2'); write 16B to my slot in buffer par
    auto fold_write = [&](int par, const float4& r0, const float4& r1) -> float {
        const float G0 = fmaf(sc0, r1.y, fmaf(sh0, r0.z, fmaf(ss0, r0.y, g0c)));
        const float G1 = fmaf(sc1, r1.z, fmaf(sh1, r0.w, fmaf(ss1, r0.y, g1c)));
        const float G2 = fmaf(sc2, r1.w, fmaf(sh2, r1.x, fmaf(ss2, r0.y, g2c)));
        *(float4*)(region + par * 64 + (l << 2)) = make_float4(r0.x, G0, G1, G2);
        return r0.x;
    };

    float4 pf0, pf1;     // raw u row for superblock sb+1, in flight
    float u0_cur;        // my own row's u0 for the CURRENT superblock

    // prologue: load+fold rows of sb=0 into buf 0; prefetch rows of sb=1
    {
        const float4* s = ub + (size_t)(l * 2);
        float4 t0 = s[0], t1 = s[1];
        u0_cur = fold_write(0, t0, t1);
        const float4* p = ub + (size_t)((SB + l) * 2);
        pf0 = p[0]; pf1 = p[1];
    }

    for (int sb = 0; sb < NSB; ++sb) {
        const int par = sb & 1;

        // fold prefetched rows of sb+1 into the other buffer
        // (sb=NSB-1: pf holds clamped duplicate rows; write lands in the
        //  never-read buffer -> harmless)
        const float u0_next = fold_write(par ^ 1, pf0, pf1);

        // prefetch rows of sb+2 (clamped) -> in flight for a full superblock
        {
            const int jj = (sb + 2 < NSB) ? (sb + 2) : (NSB - 1);
            const float4* p = ub + (size_t)((jj * SB + l) * 2);
            pf0 = p[0]; pf1 = p[1];
        }

        // 16 steps from buffer par (per-step 16B broadcast read)
        float O0 = 0.0f, O1 = 0.0f, O2 = 0.0f;
        const float* rdbase = region + par * 64;
#pragma unroll
        for (int i = 0; i < SB; ++i) {
            const float4 r = *(const float4*)(rdbase + (i << 2));
            if (l == i) { O0 = X0; O1 = X1; O2 = X2; }   // state BEFORE step i
            const float i0 = __builtin_amdgcn_rcpf(X0);
            const float i1 = __builtin_amdgcn_rcpf(X1);
            const float i2 = __builtin_amdgcn_rcpf(X2);
            const float E0 = hce0 * r.x;
            const float E1 = hce1 * r.x;
            const float E2 = hce2 * r.x;
            // p_k parallel with the rcp (depend only on X and broadcast u0)
            const float p0 = fmaf(F12_0, X1, E0);
            const float p1 = fmaf(F12_1, X0, fmaf(F23_1, X2, E1));
            const float p2 = fmaf(F23_2, X1, E2);
            const float z0 = fmaf(i0, p0, r.y);   // r.y = G0'
            const float z1 = fmaf(i1, p1, r.z);   // r.z = G1'
            const float z2 = fmaf(i2, p2, r.w);   // r.w = G2'
            X0 *= EXP2F(z0);
            X1 *= EXP2F(z1);
            X2 *= EXP2F(z2);
        }

        // store my output row t = sb*16 + l (state BEFORE step l), masked by
        // my OWN u0; t==0 is x0, never masked.
        const int t = sb * SB + l;
        const bool bad = (u0_cur < 1e-6f) && (t != 0);
        float3 o;
        o.x = bad ? -1.0f : O0;
        o.y = bad ? -1.0f : O1;
        o.z = bad ? -1.0f : O2;
        *(float3*)(ob + (size_t)t * 3) = o;

        u0_cur = u0_next;
    }
}

extern "C" void kernel_launch(void* const* d_in, const int* in_sizes, int n_in,
                              void* d_out, int out_size, void* d_ws, size_t ws_size,
                              hipStream_t stream) {
    const float* x0  = (const float*)d_in[0];   // (B,3)
    const float* u   = (const float*)d_in[1];   // (B,T,8)
    const float* lam = (const float*)d_in[2];   // (14)
    float* out = (float*)d_out;                 // (B,T,3)

    const int B = in_sizes[0] / 3;              // 8192
    const int threads = B * 16;                 // 16 lanes per chain
    dim3 grid(threads / 256), block(256);
    hipLaunchKernelGGL(bm_fwd, grid, block, 0, stream, x0, u, lam, out);
}